// Round 12
// baseline (270.120 us; speedup 1.0000x reference)
//
#include <hip/hip_runtime.h>
#include <hip/hip_bf16.h>

#define IN_CH 128
#define HID 32
#define OUT_CH 16
#define NPW 128           // nodes per bucket (col >> 7)
#define NPW_SHIFT 7
#define NB_MAX 1024
#define CAPF 12800        // fill_sort LDS edge capacity (50 KB)
#define FBT 512           // threads in hist/fill
#define CAP 12288         // csr_sort LDS edge capacity (48 KB)
#define KEYS (NPW * 2)    // (local col, src half)
#define SCAN_CHUNK 1024
#define NXCD 8
#define EPT 8

typedef int vint4 __attribute__((ext_vector_type(4)));
typedef vint4 vint4u __attribute__((aligned(4)));
typedef float vfloat2 __attribute__((ext_vector_type(2)));

// ---------------------------------------------------------------------------
__global__ void detect_dtype(const void* ei, long long ecount, int n, int* flag) {
    int lane = threadIdx.x;
    const long long* p = (const long long*)ei;
    long long st = ecount / 64; if (st < 1) st = 1;
    long long idx = (long long)lane * st;
    bool ok = true;
    if (idx < ecount) {
        long long v = p[idx];
        ok = (v >= 0 && v < n);
    }
    unsigned long long mask = __ballot(ok);
    if (lane == 0) *flag = (mask == ~0ULL) ? 1 : 0;
}

__device__ __forceinline__ int load_idx(const void* ei, long long i, int is64) {
    return is64 ? (int)((const long long*)ei)[i] : ((const int*)ei)[i];
}

__device__ __forceinline__ void load_idx8_nt(const void* ei, long long off, int is64,
                                             int* c) {
    if (is64) {
        const long long* p = (const long long*)ei + off;
#pragma unroll
        for (int j = 0; j < 8; ++j) c[j] = (int)__builtin_nontemporal_load(p + j);
    } else {
        vint4 v0 = __builtin_nontemporal_load((const vint4*)((const int*)ei + off));
        vint4 v1 = __builtin_nontemporal_load((const vint4*)((const int*)ei + off + 4));
        c[0] = v0.x; c[1] = v0.y; c[2] = v0.z; c[3] = v0.w;
        c[4] = v1.x; c[5] = v1.y; c[6] = v1.z; c[7] = v1.w;
    }
}

__device__ __forceinline__ float bf_lo(unsigned int u) { return __uint_as_float(u << 16); }
__device__ __forceinline__ float bf_hi(unsigned int u) { return __uint_as_float(u & 0xFFFF0000u); }

// ---------------------------------------------------------------------------
__global__ __launch_bounds__(256) void zero_int(int* p, int n) {
    int i = blockIdx.x * 256 + threadIdx.x;
    if (i < n) p[i] = 0;
}

__global__ __launch_bounds__(256) void zero_float(float* p, long long n) {
    long long i = (long long)blockIdx.x * 256 + threadIdx.x;
    if (i < n) p[i] = 0.f;
}

// ---------------------------------------------------------------------------
// pass A: per-block LDS histogram -> bhist[bucket*fbgrid+blk] (raw, preserved)
// ---------------------------------------------------------------------------
__global__ __launch_bounds__(FBT) void bucket_hist(const void* ei, long long E,
                                                   const int* flag, int* bhist,
                                                   int nb, long long chunk, int fbgrid) {
    __shared__ int hist[NB_MAX];
    for (int i = threadIdx.x; i < nb; i += FBT) hist[i] = 0;
    __syncthreads();
    long long lo = (long long)blockIdx.x * chunk;
    long long hi = lo + chunk; if (hi > E) hi = E;
    int is64 = *flag;
    if ((E & 7) == 0) {
        for (long long e = lo + (long long)threadIdx.x * EPT; e + EPT <= hi;
             e += (long long)FBT * EPT) {
            int c[8]; load_idx8_nt(ei, E + e, is64, c);
#pragma unroll
            for (int j = 0; j < 8; ++j) atomicAdd(&hist[c[j] >> NPW_SHIFT], 1);
        }
    } else {
        for (long long e = lo + threadIdx.x; e < hi; e += FBT)
            atomicAdd(&hist[load_idx(ei, E + e, is64) >> NPW_SHIFT], 1);
    }
    __syncthreads();
    for (int b = threadIdx.x; b < nb; b += FBT)
        bhist[(long long)b * fbgrid + blockIdx.x] = hist[b];
}

// pass B: per-bucket exclusive scan over fbgrid block counts -> bexcl (bhist
// kept raw for fill_sort) + bucket totals
__global__ __launch_bounds__(256) void scan_blocks(const int* bhist, int* bexcl,
                                                   int* btot, int nb, int fbgrid) {
    __shared__ int sd[256];
    int b = blockIdx.x, t = threadIdx.x;
    const int* p = bhist + (long long)b * fbgrid;
    int* q = bexcl + (long long)b * fbgrid;
    int running = 0;
    for (int j0 = 0; j0 < fbgrid; j0 += 256) {
        int j = j0 + t;
        int v = (j < fbgrid) ? p[j] : 0;
        sd[t] = v; __syncthreads();
        for (int off = 1; off < 256; off <<= 1) {
            int u = (t >= off) ? sd[t - off] : 0;
            __syncthreads(); sd[t] += u; __syncthreads();
        }
        if (j < fbgrid) q[j] = running + sd[t] - v;
        int tot = sd[255];
        __syncthreads();
        running += tot;
    }
    if (t == 0) btot[b] = running;
}

// pass C: exclusive scan over nb bucket totals, one block
__global__ __launch_bounds__(1024) void scan_buckets(const int* btot, int* bstart, int nb) {
    __shared__ int sd[1024];
    int t = threadIdx.x;
    int a0 = (2 * t < nb) ? btot[2 * t] : 0;
    int a1 = (2 * t + 1 < nb) ? btot[2 * t + 1] : 0;
    sd[t] = a0 + a1; __syncthreads();
    for (int off = 1; off < 1024; off <<= 1) {
        int v = (t >= off) ? sd[t - off] : 0;
        __syncthreads(); sd[t] += v; __syncthreads();
    }
    int excl = sd[t] - (a0 + a1);
    if (2 * t < nb)     bstart[2 * t] = excl;
    if (2 * t + 1 < nb) bstart[2 * t + 1] = excl + a0;
    if (t == 1023) bstart[nb] = sd[t];
}

// ---------------------------------------------------------------------------
// pass D: sort-then-burst fill. Counts come from bhist (no col re-scan);
// bucket-sort chunk in LDS; burst-write each (bucket,block) run contiguously.
// ---------------------------------------------------------------------------
__global__ __launch_bounds__(FBT) void fill_sort(const void* ei, long long E,
                                                 const int* flag, const int* bhist,
                                                 const int* bexcl, const int* bstart,
                                                 int* bucketed, int nb,
                                                 long long chunk, int fbgrid) {
    __shared__ int lds[CAPF];
    __shared__ int hist[NB_MAX];
    __shared__ int base[NB_MAX];
    __shared__ int cur[NB_MAX];
    int blk = blockIdx.x, t = threadIdx.x;
    long long lo = (long long)blk * chunk;
    long long hi = lo + chunk; if (hi > E) hi = E;
    int cnt = (int)(hi - lo);
    for (int b = t; b < nb; b += FBT)
        hist[b] = bhist[(long long)b * fbgrid + blk];
    __syncthreads();
    int is64 = *flag;
    bool vec = ((E & 7) == 0) && ((chunk & 7) == 0);

    if (cnt <= CAPF) {
        // local exclusive scan of hist (2 elems/thread, base[] as scratch)
        int a0 = (2 * t < nb) ? hist[2 * t] : 0;
        int a1 = (2 * t + 1 < nb) ? hist[2 * t + 1] : 0;
        base[t] = a0 + a1; __syncthreads();
        for (int off = 1; off < FBT; off <<= 1) {
            int u = (t >= off) ? base[t - off] : 0;
            __syncthreads(); base[t] += u; __syncthreads();
        }
        int incl = base[t];
        __syncthreads();
        int excl = incl - (a0 + a1);
        if (2 * t < nb)     { base[2 * t] = excl;          cur[2 * t] = excl; }
        if (2 * t + 1 < nb) { base[2 * t + 1] = excl + a0; cur[2 * t + 1] = excl + a0; }
        __syncthreads();

        // scatter packed entries into bucket-sorted LDS
        if (vec) {
            for (long long e = lo + (long long)t * EPT; e + EPT <= hi; e += (long long)FBT * EPT) {
                int c[8], r[8];
                load_idx8_nt(ei, E + e, is64, c);
                load_idx8_nt(ei, e, is64, r);
#pragma unroll
                for (int j = 0; j < 8; ++j) {
                    int b = c[j] >> NPW_SHIFT;
                    int p = atomicAdd(&cur[b], 1);
                    lds[p] = r[j] | ((c[j] & (NPW - 1)) << 17);
                }
            }
        } else {
            for (long long e = lo + t; e < hi; e += FBT) {
                int col = load_idx(ei, E + e, is64);
                int row = load_idx(ei, e, is64);
                int b = col >> NPW_SHIFT;
                int p = atomicAdd(&cur[b], 1);
                lds[p] = row | ((col & (NPW - 1)) << 17);
            }
        }
        __syncthreads();

        // burst-write each bucket run (16-lane groups)
        int grp = t >> 4, lane = t & 15;       // 32 groups x 16 lanes
        for (int b = grp; b < nb; b += 32) {
            int l0 = base[b], c0 = hist[b];
            if (!c0) continue;
            int g0 = bstart[b] + bexcl[(long long)b * fbgrid + blk];
            for (int j = lane; j < c0; j += 16)
                bucketed[g0 + j] = lds[l0 + j];
        }
    } else {
        // fallback: direct scatter
        for (int b = t; b < nb; b += FBT)
            cur[b] = bstart[b] + bexcl[(long long)b * fbgrid + blk];
        __syncthreads();
        for (long long e = lo + t; e < hi; e += FBT) {
            int col = load_idx(ei, E + e, is64);
            int row = load_idx(ei, e, is64);
            int b = col >> NPW_SHIFT;
            int p = atomicAdd(&cur[b], 1);
            bucketed[p] = row | ((col & (NPW - 1)) << 17);
        }
    }
}

// ---------------------------------------------------------------------------
// per-bucket node sort, keyed by (local col, src half): emits offs/mid/dinv +
// node-and-half-sorted csr (rows only). mid enables the L2-resident agg split.
// ---------------------------------------------------------------------------
__global__ __launch_bounds__(512) void csr_sort(const int* __restrict__ bucketed,
                                                const int* __restrict__ bstart,
                                                int* __restrict__ csr,
                                                int* __restrict__ offs,
                                                int* __restrict__ mid,
                                                float* __restrict__ dinv,
                                                int nb, int n, int nhalf) {
    __shared__ int lds_e[CAP];
    __shared__ int histk[KEYS];
    __shared__ int cur[KEYS];
    int b = blockIdx.x, t = threadIdx.x;
    int s0 = bstart[b], s1 = bstart[b + 1];
    int cnt = s1 - s0;
    if (t < KEYS) histk[t] = 0;
    __syncthreads();
    bool fit = (cnt <= CAP);
    int cnt4 = cnt & ~3;
    auto key = [&](int e) {
        return (((e >> 17) & (NPW - 1)) << 1) | (((e & 0x1FFFF) >= nhalf) ? 1 : 0);
    };
    if (fit) {
        for (int i = t * 4; i < cnt4; i += 2048) {
            vint4u e4 = *(const vint4u*)(bucketed + s0 + i);
            lds_e[i + 0] = e4.x; atomicAdd(&histk[key(e4.x)], 1);
            lds_e[i + 1] = e4.y; atomicAdd(&histk[key(e4.y)], 1);
            lds_e[i + 2] = e4.z; atomicAdd(&histk[key(e4.z)], 1);
            lds_e[i + 3] = e4.w; atomicAdd(&histk[key(e4.w)], 1);
        }
        for (int i = cnt4 + t; i < cnt; i += 512) {
            int e = bucketed[s0 + i];
            lds_e[i] = e;
            atomicAdd(&histk[key(e)], 1);
        }
    } else {
        for (int i = t * 4; i < cnt4; i += 2048) {
            vint4u e4 = *(const vint4u*)(bucketed + s0 + i);
            atomicAdd(&histk[key(e4.x)], 1);
            atomicAdd(&histk[key(e4.y)], 1);
            atomicAdd(&histk[key(e4.z)], 1);
            atomicAdd(&histk[key(e4.w)], 1);
        }
        for (int i = cnt4 + t; i < cnt; i += 512)
            atomicAdd(&histk[key(bucketed[s0 + i])], 1);
    }
    __syncthreads();
    if (t == 0) {
        int run = 0;
        for (int k = 0; k < KEYS; ++k) { cur[k] = run; run += histk[k]; }
    }
    __syncthreads();
    if (t < NPW) {
        int node = b * NPW + t;
        if (node < n) {
            offs[node] = s0 + cur[2 * t];
            mid[node]  = s0 + cur[2 * t] + histk[2 * t];
            dinv[node] = 1.0f / sqrtf((float)(histk[2 * t] + histk[2 * t + 1] + 1));
        }
    }
    if (b == nb - 1 && t == 0) offs[n] = s1;
    __syncthreads();
    if (fit) {
        for (int i = t; i < cnt; i += 512) {
            int e = lds_e[i];
            int pos = atomicAdd(&cur[key(e)], 1);
            csr[s0 + pos] = e & 0x1FFFF;
        }
    } else {
        for (int i = t; i < cnt; i += 512) {
            int e = bucketed[s0 + i];
            int pos = atomicAdd(&cur[key(e)], 1);
            csr[s0 + pos] = e & 0x1FFFF;
        }
    }
}

// ---------------------------------------------------------------------------
// GEMMs, dinv pre-multiplied; BF16=1 writes bf16 (halves agg gather bytes)
// ---------------------------------------------------------------------------
template <int BF16>
__global__ __launch_bounds__(256) void gemm1p(const float* __restrict__ x,
                                              const float* __restrict__ W1,
                                              const float* __restrict__ dinv,
                                              float* __restrict__ m1f,
                                              __hip_bfloat16* __restrict__ m1b, int n) {
    __shared__ float sW[IN_CH * HID];
    __shared__ float sx[8][IN_CH];
    for (int i = threadIdx.x; i < IN_CH * HID; i += 256) sW[i] = W1[i];
    int g = threadIdx.x >> 5;
    int c = threadIdx.x & 31;
    long long node = (long long)blockIdx.x * 8 + g;
    bool active = node < n;
    if (active) {
        const float4* xr = (const float4*)(x + node * IN_CH);
        float4 v = xr[c];
        sx[g][c * 4 + 0] = v.x; sx[g][c * 4 + 1] = v.y;
        sx[g][c * 4 + 2] = v.z; sx[g][c * 4 + 3] = v.w;
    }
    __syncthreads();
    if (!active) return;
    float acc = 0.f;
#pragma unroll
    for (int k = 0; k < IN_CH; ++k)
        acc = fmaf(sx[g][k], sW[k * HID + c], acc);
    float v = acc * dinv[node];
    if (BF16) m1b[(node << 5) + c] = __float2bfloat16(v);
    else      m1f[(node << 5) + c] = v;
}

template <int BF16>
__global__ __launch_bounds__(256) void gemm2p(const float* __restrict__ h,
                                              const float* __restrict__ W2,
                                              const float* __restrict__ dinv,
                                              float* __restrict__ m2f,
                                              __hip_bfloat16* __restrict__ m2b, int n) {
    __shared__ float sW[HID * OUT_CH];
    for (int i = threadIdx.x; i < HID * OUT_CH; i += 256) sW[i] = W2[i];
    __syncthreads();
    long long t = (long long)blockIdx.x * 256 + threadIdx.x;
    long long node = t >> 4;
    int c = (int)(t & 15);
    if (node >= n) return;
    const float* hr = h + node * HID;
    float acc = 0.f;
#pragma unroll
    for (int k = 0; k < HID; ++k)
        acc = fmaf(hr[k], sW[k * OUT_CH + c], acc);
    float v = acc * dinv[node];
    if (BF16) m2b[(node << 4) + c] = __float2bfloat16(v);
    else      m2f[(node << 4) + c] = v;
}

// ---------------------------------------------------------------------------
// bf16 CSR gather aggregation, source-half split:
// MODE 0: gather [offs,mid) (src < nhalf, 3.2MB table half L2-resident),
//         write raw partials to h (nontemporal — don't evict the table).
// MODE 1: gather [mid,offs+1), add partials + self + bias, ReLU, store.
// MODE 2: single pass (tier2 path without mid).
// ---------------------------------------------------------------------------
template <int MODE>
__global__ __launch_bounds__(256) void agg1_bf(const unsigned int* __restrict__ m1b,
                                               const int* __restrict__ csr,
                                               const int* __restrict__ offs,
                                               const int* __restrict__ mid,
                                               const float* __restrict__ dinv,
                                               const float* __restrict__ b1,
                                               float* __restrict__ h, int n) {
    int g = threadIdx.x >> 4;
    int c = threadIdx.x & 15;
    long long node = (long long)blockIdx.x * 16 + g;
    if (node >= n) return;
    int s, e1;
    if (MODE == 0)      { s = offs[node]; e1 = mid[node]; }
    else if (MODE == 1) { s = mid[node];  e1 = offs[node + 1]; }
    else                { s = offs[node]; e1 = offs[node + 1]; }
    float accL, accH;
    if (MODE == 0) { accL = 0.f; accH = 0.f; }
    else {
        unsigned int us = m1b[(node << 4) + c];      // self loop
        accL = bf_lo(us); accH = bf_hi(us);
    }
    for (; s + 7 < e1; s += 8) {
        vint4u a = *(const vint4u*)(csr + s);
        vint4u b = *(const vint4u*)(csr + s + 4);
        unsigned int u0 = m1b[((long long)a.x << 4) + c];
        unsigned int u1 = m1b[((long long)a.y << 4) + c];
        unsigned int u2 = m1b[((long long)a.z << 4) + c];
        unsigned int u3 = m1b[((long long)a.w << 4) + c];
        unsigned int u4 = m1b[((long long)b.x << 4) + c];
        unsigned int u5 = m1b[((long long)b.y << 4) + c];
        unsigned int u6 = m1b[((long long)b.z << 4) + c];
        unsigned int u7 = m1b[((long long)b.w << 4) + c];
        accL += bf_lo(u0); accH += bf_hi(u0);
        accL += bf_lo(u1); accH += bf_hi(u1);
        accL += bf_lo(u2); accH += bf_hi(u2);
        accL += bf_lo(u3); accH += bf_hi(u3);
        accL += bf_lo(u4); accH += bf_hi(u4);
        accL += bf_lo(u5); accH += bf_hi(u5);
        accL += bf_lo(u6); accH += bf_hi(u6);
        accL += bf_lo(u7); accH += bf_hi(u7);
    }
    for (; s < e1; ++s) {
        unsigned int u = m1b[((long long)csr[s] << 4) + c];
        accL += bf_lo(u); accH += bf_hi(u);
    }
    if (MODE == 0) {
        vfloat2 val; val.x = accL; val.y = accH;
        __builtin_nontemporal_store(val, (vfloat2*)(h + (node << 5) + 2 * c));
    } else {
        if (MODE == 1) {
            vfloat2 prev = __builtin_nontemporal_load((const vfloat2*)(h + (node << 5) + 2 * c));
            accL += prev.x; accH += prev.y;
        }
        float di = dinv[node];
        float vL = accL * di + b1[2 * c];
        float vH = accH * di + b1[2 * c + 1];
        vfloat2 val;
        val.x = vL > 0.f ? vL : 0.f;
        val.y = vH > 0.f ? vH : 0.f;
        *(vfloat2*)(h + (node << 5) + 2 * c) = val;
    }
}

__global__ __launch_bounds__(256) void agg2_bf(const unsigned int* __restrict__ m2b,
                                               const int* __restrict__ csr,
                                               const int* __restrict__ offs,
                                               const float* __restrict__ dinv,
                                               const float* __restrict__ b2,
                                               float* __restrict__ out, int n) {
    int g = threadIdx.x >> 3;
    int c = threadIdx.x & 7;
    long long node = (long long)blockIdx.x * 32 + g;
    if (node >= n) return;
    unsigned int us = m2b[(node << 3) + c];
    float accL = bf_lo(us), accH = bf_hi(us);
    int s = offs[node], e1 = offs[node + 1];
    for (; s + 7 < e1; s += 8) {
        vint4u a = *(const vint4u*)(csr + s);
        vint4u b = *(const vint4u*)(csr + s + 4);
        unsigned int u0 = m2b[((long long)a.x << 3) + c];
        unsigned int u1 = m2b[((long long)a.y << 3) + c];
        unsigned int u2 = m2b[((long long)a.z << 3) + c];
        unsigned int u3 = m2b[((long long)a.w << 3) + c];
        unsigned int u4 = m2b[((long long)b.x << 3) + c];
        unsigned int u5 = m2b[((long long)b.y << 3) + c];
        unsigned int u6 = m2b[((long long)b.z << 3) + c];
        unsigned int u7 = m2b[((long long)b.w << 3) + c];
        accL += bf_lo(u0); accH += bf_hi(u0);
        accL += bf_lo(u1); accH += bf_hi(u1);
        accL += bf_lo(u2); accH += bf_hi(u2);
        accL += bf_lo(u3); accH += bf_hi(u3);
        accL += bf_lo(u4); accH += bf_hi(u4);
        accL += bf_lo(u5); accH += bf_hi(u5);
        accL += bf_lo(u6); accH += bf_hi(u6);
        accL += bf_lo(u7); accH += bf_hi(u7);
    }
    for (; s < e1; ++s) {
        unsigned int u = m2b[((long long)csr[s] << 3) + c];
        accL += bf_lo(u); accH += bf_hi(u);
    }
    float di = dinv[node];
    vfloat2 val;
    val.x = accL * di + b2[2 * c];
    val.y = accH * di + b2[2 * c + 1];
    *(vfloat2*)(out + (node << 4) + 2 * c) = val;
}

// ---------------------------------------------------------------------------
// tier 2: windowed CSR fill path
// ---------------------------------------------------------------------------
__global__ __launch_bounds__(256) void count_edges(const void* ei, int* cnt,
                                                   long long E, const int* flag) {
    long long e0 = ((long long)blockIdx.x * 256 + threadIdx.x) * EPT;
    if (e0 >= E) return;
    int is64 = *flag;
    if (e0 + EPT <= E && (E & 7) == 0) {
        int c[EPT];
        load_idx8_nt(ei, E + e0, is64, c);
#pragma unroll
        for (int j = 0; j < EPT; ++j) atomicAdd(&cnt[c[j]], 1);
    } else {
        for (long long e = e0; e < E && e < e0 + EPT; ++e)
            atomicAdd(&cnt[load_idx(ei, E + e, is64)], 1);
    }
}

__global__ __launch_bounds__(256) void compute_dinv(const int* cnt, float* dinv, int n) {
    int i = blockIdx.x * 256 + threadIdx.x;
    if (i < n) dinv[i] = 1.0f / sqrtf((float)(cnt[i] + 1));
}

__global__ __launch_bounds__(256) void scan_partial(const int* cnt, int* partial, int n) {
    __shared__ int sd[256];
    int base = blockIdx.x * SCAN_CHUNK;
    int s = 0;
    for (int j = threadIdx.x; j < SCAN_CHUNK; j += 256) {
        int i = base + j;
        if (i < n) s += cnt[i];
    }
    sd[threadIdx.x] = s;
    __syncthreads();
    for (int off = 128; off > 0; off >>= 1) {
        if (threadIdx.x < off) sd[threadIdx.x] += sd[threadIdx.x + off];
        __syncthreads();
    }
    if (threadIdx.x == 0) partial[blockIdx.x] = sd[0];
}

__global__ void scan_serial(int* partial, int* offs, int nblk, int n) {
    if (threadIdx.x == 0 && blockIdx.x == 0) {
        int run = 0;
        for (int b = 0; b < nblk; ++b) { int t = partial[b]; partial[b] = run; run += t; }
        offs[n] = run;
    }
}

__global__ __launch_bounds__(256) void scan_final(const int* cnt, const int* partial,
                                                  int* offs, int n) {
    __shared__ int sd[256];
    int base = blockIdx.x * SCAN_CHUNK;
    int t = threadIdx.x;
    int loc[4]; int ts = 0;
#pragma unroll
    for (int j = 0; j < 4; ++j) {
        int i = base + t * 4 + j;
        loc[j] = (i < n) ? cnt[i] : 0;
        ts += loc[j];
    }
    sd[t] = ts;
    __syncthreads();
    for (int off = 1; off < 256; off <<= 1) {
        int v = (t >= off) ? sd[t - off] : 0;
        __syncthreads();
        sd[t] += v;
        __syncthreads();
    }
    int excl = sd[t] - ts + partial[blockIdx.x];
#pragma unroll
    for (int j = 0; j < 4; ++j) {
        int i = base + t * 4 + j;
        if (i < n) offs[i] = excl;
        excl += loc[j];
    }
}

__global__ __launch_bounds__(256) void copy_int(const int* src, int* dst, int n) {
    int i = blockIdx.x * 256 + threadIdx.x;
    if (i < n) dst[i] = src[i];
}

__global__ __launch_bounds__(256) void fill_csr_win(const void* ei, int* cursor, int* csr,
                                                    long long E, const int* flag,
                                                    int npw, int n) {
    int w = blockIdx.x & (NXCD - 1);
    int b = blockIdx.x >> 3;
    int lo = w * npw;
    int hi = lo + npw; if (hi > n) hi = n;
    long long e0 = ((long long)b * 256 + threadIdx.x) * EPT;
    if (e0 >= E) return;
    int is64 = *flag;
    if (e0 + EPT <= E && (E & 7) == 0) {
        int c[EPT];
        load_idx8_nt(ei, E + e0, is64, c);
#pragma unroll
        for (int j = 0; j < EPT; ++j) {
            if (c[j] >= lo && c[j] < hi) {
                int row = load_idx(ei, e0 + j, is64);
                int pos = atomicAdd(&cursor[c[j]], 1);
                csr[pos] = row;
            }
        }
    } else {
        for (long long e = e0; e < E && e < e0 + EPT; ++e) {
            int col = load_idx(ei, E + e, is64);
            if (col >= lo && col < hi) {
                int row = load_idx(ei, e, is64);
                int pos = atomicAdd(&cursor[col], 1);
                csr[pos] = row;
            }
        }
    }
}

// ---------------------------------------------------------------------------
// tier 3: scatter fallback (fp32, m pre-scaled)
// ---------------------------------------------------------------------------
__global__ __launch_bounds__(256) void scatter1(const float* __restrict__ m1s,
                                                const void* ei,
                                                float* __restrict__ h,
                                                long long E, const int* flag) {
    long long e = (long long)blockIdx.x * 8 + (threadIdx.x >> 5);
    int c = threadIdx.x & 31;
    if (e >= E) return;
    int is64 = *flag;
    int row = load_idx(ei, e, is64);
    int col = load_idx(ei, E + e, is64);
    atomicAdd(&h[(long long)col * HID + c], m1s[(long long)row * HID + c]);
}

__global__ __launch_bounds__(256) void fixup1(const float* __restrict__ m1s,
                                              const float* __restrict__ dinv,
                                              const float* __restrict__ b1,
                                              float* __restrict__ h, int n) {
    long long t = (long long)blockIdx.x * 256 + threadIdx.x;
    long long node = t >> 5; int c = (int)(t & 31);
    if (node >= n) return;
    float v = (h[node * HID + c] + m1s[node * HID + c]) * dinv[node] + b1[c];
    h[node * HID + c] = v > 0.f ? v : 0.f;
}

__global__ __launch_bounds__(256) void scatter2(const float* __restrict__ m2s,
                                                const void* ei,
                                                float* __restrict__ out,
                                                long long E, const int* flag) {
    long long e = (long long)blockIdx.x * 16 + (threadIdx.x >> 4);
    int c = threadIdx.x & 15;
    if (e >= E) return;
    int is64 = *flag;
    int row = load_idx(ei, e, is64);
    int col = load_idx(ei, E + e, is64);
    atomicAdd(&out[(long long)col * OUT_CH + c], m2s[(long long)row * OUT_CH + c]);
}

__global__ __launch_bounds__(256) void fixup2(const float* __restrict__ m2s,
                                              const float* __restrict__ dinv,
                                              const float* __restrict__ b2,
                                              float* __restrict__ out, int n) {
    long long t = (long long)blockIdx.x * 256 + threadIdx.x;
    long long node = t >> 4; int c = (int)(t & 15);
    if (node >= n) return;
    out[node * OUT_CH + c] = (out[node * OUT_CH + c] + m2s[node * OUT_CH + c]) * dinv[node] + b2[c];
}

// ---------------------------------------------------------------------------
extern "C" void kernel_launch(void* const* d_in, const int* in_sizes, int n_in,
                              void* d_out, int out_size, void* d_ws, size_t ws_size,
                              hipStream_t stream) {
    const float* x  = (const float*)d_in[0];
    const void*  ei = d_in[1];
    const float* W1 = (const float*)d_in[2];
    const float* b1 = (const float*)d_in[3];
    const float* W2 = (const float*)d_in[4];
    const float* b2 = (const float*)d_in[5];
    float* out = (float*)d_out;

    const int n = in_sizes[0] / IN_CH;           // 100000
    const long long E = in_sizes[1] / 2;         // 6400000
    const int nb = (n + NPW - 1) / NPW;          // 782
    const int nhalf = (n + 1) / 2;

    const long long chunkF = (((E + 511) / 512) + 7) & ~7LL;
    const int fbgrid = (int)((E + chunkF - 1) / chunkF);

    char* w = (char*)d_ws;
    size_t used = 0;
    auto carve = [&](size_t bytes) -> void* {
        void* p = (void*)(w + used);
        used += (bytes + 255) & ~(size_t)255;
        return p;
    };
    auto A = [](size_t b) -> size_t { return (b + 255) & ~(size_t)255; };

    int*   bstart  = (int*)carve((size_t)(NB_MAX + 1) * 4);
    int*   btot    = (int*)carve((size_t)NB_MAX * 4);
    float* dinv    = (float*)carve((size_t)n * 4);
    int*   flag    = (int*)carve(256);
    int*   offs    = (int*)carve((size_t)(n + 1) * 4);
    int*   mid     = (int*)carve((size_t)n * 4);
    int*   cnt     = (int*)carve((size_t)n * 4);
    int*   partial = (int*)carve(4096);
    const size_t base = used;

    const size_t bhistB = A((size_t)nb * fbgrid * 4);
    const size_t mbB    = A((size_t)n * HID * 2);   // bf16 m1 (reused as m2)
    const size_t hB     = A((size_t)n * HID * 4);
    const size_t needT1 = base + 2 * bhistB + 2 * A((size_t)E * 4) + mbB + hB;
    const size_t needT2 = base + A((size_t)E * 4) + mbB + hB;
    const size_t needT3 = base + 2 * A((size_t)n * HID * 4);
    const bool tier1 = (ws_size >= needT1) && (n <= 131071) && (nb <= NB_MAX);
    const bool tier2 = !tier1 && (ws_size >= needT2) && (n <= 131071);

    const int nblkN  = (n + 255) / 256;
    const int nblkEv = (int)((E + 256LL * EPT - 1) / (256LL * EPT));
    const int nblkSc = (n + SCAN_CHUNK - 1) / SCAN_CHUNK;
    const int nblkH  = (int)(((long long)n * HID + 255) / 256);
    const int nblkO  = (int)(((long long)n * OUT_CH + 255) / 256);

    detect_dtype<<<1, 64, 0, stream>>>(ei, E, n, flag);

    if (tier1) {
        int*   bhist    = (int*)carve((size_t)nb * fbgrid * 4);
        int*   bexcl    = (int*)carve((size_t)nb * fbgrid * 4);
        int*   bucketed = (int*)carve((size_t)E * 4);
        int*   csr      = (int*)carve((size_t)E * 4);
        __hip_bfloat16* m1b = (__hip_bfloat16*)carve((size_t)n * HID * 2);
        float* h  = (float*)carve((size_t)n * HID * 4);
        __hip_bfloat16* m2b = m1b;                 // m1b dead after agg1

        bucket_hist<<<fbgrid, FBT, 0, stream>>>(ei, E, flag, bhist, nb, chunkF, fbgrid);
        scan_blocks<<<nb, 256, 0, stream>>>(bhist, bexcl, btot, nb, fbgrid);
        scan_buckets<<<1, 1024, 0, stream>>>(btot, bstart, nb);
        fill_sort<<<fbgrid, FBT, 0, stream>>>(ei, E, flag, bhist, bexcl, bstart,
                                              bucketed, nb, chunkF, fbgrid);
        csr_sort<<<nb, 512, 0, stream>>>(bucketed, bstart, csr, offs, mid, dinv,
                                         nb, n, nhalf);

        gemm1p<1><<<(n + 7) / 8, 256, 0, stream>>>(x, W1, dinv, nullptr, m1b, n);
        agg1_bf<0><<<(n + 15) / 16, 256, 0, stream>>>((const unsigned int*)m1b, csr,
                                                      offs, mid, dinv, b1, h, n);
        agg1_bf<1><<<(n + 15) / 16, 256, 0, stream>>>((const unsigned int*)m1b, csr,
                                                      offs, mid, dinv, b1, h, n);
        gemm2p<1><<<nblkO, 256, 0, stream>>>(h, W2, dinv, nullptr, m2b, n);
        agg2_bf<<<(n + 31) / 32, 256, 0, stream>>>((const unsigned int*)m2b, csr, offs,
                                                   dinv, b2, out, n);
    } else if (tier2) {
        int*   csr = (int*)carve((size_t)E * 4);
        __hip_bfloat16* m1b = (__hip_bfloat16*)carve((size_t)n * HID * 2);
        float* h  = (float*)carve((size_t)n * HID * 4);
        __hip_bfloat16* m2b = m1b;

        zero_int<<<nblkN, 256, 0, stream>>>(cnt, n);
        count_edges<<<nblkEv, 256, 0, stream>>>(ei, cnt, E, flag);
        compute_dinv<<<nblkN, 256, 0, stream>>>(cnt, dinv, n);
        scan_partial<<<nblkSc, 256, 0, stream>>>(cnt, partial, n);
        scan_serial<<<1, 64, 0, stream>>>(partial, offs, nblkSc, n);
        scan_final<<<nblkSc, 256, 0, stream>>>(cnt, partial, offs, n);
        copy_int<<<nblkN, 256, 0, stream>>>(offs, cnt, n);

        const int npw2 = (n + NXCD - 1) / NXCD;
        fill_csr_win<<<nblkEv * NXCD, 256, 0, stream>>>(ei, cnt, csr, E, flag, npw2, n);

        gemm1p<1><<<(n + 7) / 8, 256, 0, stream>>>(x, W1, dinv, nullptr, m1b, n);
        agg1_bf<2><<<(n + 15) / 16, 256, 0, stream>>>((const unsigned int*)m1b, csr,
                                                      offs, offs, dinv, b1, h, n);
        gemm2p<1><<<nblkO, 256, 0, stream>>>(h, W2, dinv, nullptr, m2b, n);
        agg2_bf<<<(n + 31) / 32, 256, 0, stream>>>((const unsigned int*)m2b, csr, offs,
                                                   dinv, b2, out, n);
    } else if (ws_size >= needT3) {
        float* m1 = (float*)carve((size_t)n * HID * 4);
        float* h  = (float*)carve((size_t)n * HID * 4);
        float* m2 = m1;

        zero_int<<<nblkN, 256, 0, stream>>>(cnt, n);
        count_edges<<<nblkEv, 256, 0, stream>>>(ei, cnt, E, flag);
        compute_dinv<<<nblkN, 256, 0, stream>>>(cnt, dinv, n);

        gemm1p<0><<<(n + 7) / 8, 256, 0, stream>>>(x, W1, dinv, m1, nullptr, n);
        zero_float<<<nblkH, 256, 0, stream>>>(h, (long long)n * HID);
        scatter1<<<(int)((E + 7) / 8), 256, 0, stream>>>(m1, ei, h, E, flag);
        fixup1<<<nblkH, 256, 0, stream>>>(m1, dinv, b1, h, n);
        gemm2p<0><<<nblkO, 256, 0, stream>>>(h, W2, dinv, m2, nullptr, n);
        zero_float<<<nblkO, 256, 0, stream>>>(out, (long long)n * OUT_CH);
        scatter2<<<(int)((E + 15) / 16), 256, 0, stream>>>(m2, ei, out, E, flag);
        fixup2<<<nblkO, 256, 0, stream>>>(m2, dinv, b2, out, n);
    }
}

// Round 13
// 261.214 us; speedup vs baseline: 1.0341x; 1.0341x over previous
//
#include <hip/hip_runtime.h>
#include <hip/hip_bf16.h>

#define IN_CH 128
#define HID 32
#define OUT_CH 16
#define NPW 128           // nodes per bucket (col >> 7)
#define NPW_SHIFT 7
#define NB_MAX 1024
#define CAPF 12800        // fill_sort LDS edge capacity (50 KB)
#define FBT 512           // threads in hist/fill
#define CAP 12288         // csr_sort LDS edge capacity (48 KB)
#define KEYS (NPW * 2)    // (local col, src half)
#define SCAN_CHUNK 1024
#define NXCD 8
#define EPT 8

typedef int vint4 __attribute__((ext_vector_type(4)));
typedef vint4 vint4u __attribute__((aligned(4)));
typedef float vfloat2 __attribute__((ext_vector_type(2)));

// ---------------------------------------------------------------------------
__global__ void detect_dtype(const void* ei, long long ecount, int n, int* flag) {
    int lane = threadIdx.x;
    const long long* p = (const long long*)ei;
    long long st = ecount / 64; if (st < 1) st = 1;
    long long idx = (long long)lane * st;
    bool ok = true;
    if (idx < ecount) {
        long long v = p[idx];
        ok = (v >= 0 && v < n);
    }
    unsigned long long mask = __ballot(ok);
    if (lane == 0) *flag = (mask == ~0ULL) ? 1 : 0;
}

__device__ __forceinline__ int load_idx(const void* ei, long long i, int is64) {
    return is64 ? (int)((const long long*)ei)[i] : ((const int*)ei)[i];
}

__device__ __forceinline__ void load_idx8_nt(const void* ei, long long off, int is64,
                                             int* c) {
    if (is64) {
        const long long* p = (const long long*)ei + off;
#pragma unroll
        for (int j = 0; j < 8; ++j) c[j] = (int)__builtin_nontemporal_load(p + j);
    } else {
        vint4 v0 = __builtin_nontemporal_load((const vint4*)((const int*)ei + off));
        vint4 v1 = __builtin_nontemporal_load((const vint4*)((const int*)ei + off + 4));
        c[0] = v0.x; c[1] = v0.y; c[2] = v0.z; c[3] = v0.w;
        c[4] = v1.x; c[5] = v1.y; c[6] = v1.z; c[7] = v1.w;
    }
}

__device__ __forceinline__ float bf_lo(unsigned int u) { return __uint_as_float(u << 16); }
__device__ __forceinline__ float bf_hi(unsigned int u) { return __uint_as_float(u & 0xFFFF0000u); }

__device__ __forceinline__ unsigned int pack_bf16(float a, float b) {
    __hip_bfloat16 ha = __float2bfloat16(a), hb = __float2bfloat16(b);
    unsigned short ua = *reinterpret_cast<unsigned short*>(&ha);
    unsigned short ub = *reinterpret_cast<unsigned short*>(&hb);
    return (unsigned int)ua | ((unsigned int)ub << 16);
}

// ---------------------------------------------------------------------------
__global__ __launch_bounds__(256) void zero_int(int* p, int n) {
    int i = blockIdx.x * 256 + threadIdx.x;
    if (i < n) p[i] = 0;
}

__global__ __launch_bounds__(256) void zero_float(float* p, long long n) {
    long long i = (long long)blockIdx.x * 256 + threadIdx.x;
    if (i < n) p[i] = 0.f;
}

// ---------------------------------------------------------------------------
// pass A: per-block LDS histogram -> bhist[bucket*fbgrid+blk] (raw, preserved)
// ---------------------------------------------------------------------------
__global__ __launch_bounds__(FBT) void bucket_hist(const void* ei, long long E,
                                                   const int* flag, int* bhist,
                                                   int nb, long long chunk, int fbgrid) {
    __shared__ int hist[NB_MAX];
    for (int i = threadIdx.x; i < nb; i += FBT) hist[i] = 0;
    __syncthreads();
    long long lo = (long long)blockIdx.x * chunk;
    long long hi = lo + chunk; if (hi > E) hi = E;
    int is64 = *flag;
    if ((E & 7) == 0) {
        for (long long e = lo + (long long)threadIdx.x * EPT; e + EPT <= hi;
             e += (long long)FBT * EPT) {
            int c[8]; load_idx8_nt(ei, E + e, is64, c);
#pragma unroll
            for (int j = 0; j < 8; ++j) atomicAdd(&hist[c[j] >> NPW_SHIFT], 1);
        }
    } else {
        for (long long e = lo + threadIdx.x; e < hi; e += FBT)
            atomicAdd(&hist[load_idx(ei, E + e, is64) >> NPW_SHIFT], 1);
    }
    __syncthreads();
    for (int b = threadIdx.x; b < nb; b += FBT)
        bhist[(long long)b * fbgrid + blockIdx.x] = hist[b];
}

// pass B: per-bucket exclusive scan over fbgrid block counts -> bexcl + totals
__global__ __launch_bounds__(256) void scan_blocks(const int* bhist, int* bexcl,
                                                   int* btot, int nb, int fbgrid) {
    __shared__ int sd[256];
    int b = blockIdx.x, t = threadIdx.x;
    const int* p = bhist + (long long)b * fbgrid;
    int* q = bexcl + (long long)b * fbgrid;
    int running = 0;
    for (int j0 = 0; j0 < fbgrid; j0 += 256) {
        int j = j0 + t;
        int v = (j < fbgrid) ? p[j] : 0;
        sd[t] = v; __syncthreads();
        for (int off = 1; off < 256; off <<= 1) {
            int u = (t >= off) ? sd[t - off] : 0;
            __syncthreads(); sd[t] += u; __syncthreads();
        }
        if (j < fbgrid) q[j] = running + sd[t] - v;
        int tot = sd[255];
        __syncthreads();
        running += tot;
    }
    if (t == 0) btot[b] = running;
}

// pass C: exclusive scan over nb bucket totals, one block
__global__ __launch_bounds__(1024) void scan_buckets(const int* btot, int* bstart, int nb) {
    __shared__ int sd[1024];
    int t = threadIdx.x;
    int a0 = (2 * t < nb) ? btot[2 * t] : 0;
    int a1 = (2 * t + 1 < nb) ? btot[2 * t + 1] : 0;
    sd[t] = a0 + a1; __syncthreads();
    for (int off = 1; off < 1024; off <<= 1) {
        int v = (t >= off) ? sd[t - off] : 0;
        __syncthreads(); sd[t] += v; __syncthreads();
    }
    int excl = sd[t] - (a0 + a1);
    if (2 * t < nb)     bstart[2 * t] = excl;
    if (2 * t + 1 < nb) bstart[2 * t + 1] = excl + a0;
    if (t == 1023) bstart[nb] = sd[t];
}

// ---------------------------------------------------------------------------
// pass D: sort-then-burst fill (counts from bhist; no col re-scan)
// ---------------------------------------------------------------------------
__global__ __launch_bounds__(FBT) void fill_sort(const void* ei, long long E,
                                                 const int* flag, const int* bhist,
                                                 const int* bexcl, const int* bstart,
                                                 int* bucketed, int nb,
                                                 long long chunk, int fbgrid) {
    __shared__ int lds[CAPF];
    __shared__ int hist[NB_MAX];
    __shared__ int base[NB_MAX];
    __shared__ int cur[NB_MAX];
    int blk = blockIdx.x, t = threadIdx.x;
    long long lo = (long long)blk * chunk;
    long long hi = lo + chunk; if (hi > E) hi = E;
    int cnt = (int)(hi - lo);
    for (int b = t; b < nb; b += FBT)
        hist[b] = bhist[(long long)b * fbgrid + blk];
    __syncthreads();
    int is64 = *flag;
    bool vec = ((E & 7) == 0) && ((chunk & 7) == 0);

    if (cnt <= CAPF) {
        int a0 = (2 * t < nb) ? hist[2 * t] : 0;
        int a1 = (2 * t + 1 < nb) ? hist[2 * t + 1] : 0;
        base[t] = a0 + a1; __syncthreads();
        for (int off = 1; off < FBT; off <<= 1) {
            int u = (t >= off) ? base[t - off] : 0;
            __syncthreads(); base[t] += u; __syncthreads();
        }
        int incl = base[t];
        __syncthreads();
        int excl = incl - (a0 + a1);
        if (2 * t < nb)     { base[2 * t] = excl;          cur[2 * t] = excl; }
        if (2 * t + 1 < nb) { base[2 * t + 1] = excl + a0; cur[2 * t + 1] = excl + a0; }
        __syncthreads();

        if (vec) {
            for (long long e = lo + (long long)t * EPT; e + EPT <= hi; e += (long long)FBT * EPT) {
                int c[8], r[8];
                load_idx8_nt(ei, E + e, is64, c);
                load_idx8_nt(ei, e, is64, r);
#pragma unroll
                for (int j = 0; j < 8; ++j) {
                    int b = c[j] >> NPW_SHIFT;
                    int p = atomicAdd(&cur[b], 1);
                    lds[p] = r[j] | ((c[j] & (NPW - 1)) << 17);
                }
            }
        } else {
            for (long long e = lo + t; e < hi; e += FBT) {
                int col = load_idx(ei, E + e, is64);
                int row = load_idx(ei, e, is64);
                int b = col >> NPW_SHIFT;
                int p = atomicAdd(&cur[b], 1);
                lds[p] = row | ((col & (NPW - 1)) << 17);
            }
        }
        __syncthreads();

        int grp = t >> 4, lane = t & 15;       // 32 groups x 16 lanes
        for (int b = grp; b < nb; b += 32) {
            int l0 = base[b], c0 = hist[b];
            if (!c0) continue;
            int g0 = bstart[b] + bexcl[(long long)b * fbgrid + blk];
            for (int j = lane; j < c0; j += 16)
                bucketed[g0 + j] = lds[l0 + j];
        }
    } else {
        for (int b = t; b < nb; b += FBT)
            cur[b] = bstart[b] + bexcl[(long long)b * fbgrid + blk];
        __syncthreads();
        for (long long e = lo + t; e < hi; e += FBT) {
            int col = load_idx(ei, E + e, is64);
            int row = load_idx(ei, e, is64);
            int b = col >> NPW_SHIFT;
            int p = atomicAdd(&cur[b], 1);
            bucketed[p] = row | ((col & (NPW - 1)) << 17);
        }
    }
}

// ---------------------------------------------------------------------------
// per-bucket node sort, keyed by (local col, src half): offs/mid/dinv + csr
// ---------------------------------------------------------------------------
__global__ __launch_bounds__(512) void csr_sort(const int* __restrict__ bucketed,
                                                const int* __restrict__ bstart,
                                                int* __restrict__ csr,
                                                int* __restrict__ offs,
                                                int* __restrict__ mid,
                                                float* __restrict__ dinv,
                                                int nb, int n, int nhalf) {
    __shared__ int lds_e[CAP];
    __shared__ int histk[KEYS];
    __shared__ int cur[KEYS];
    int b = blockIdx.x, t = threadIdx.x;
    int s0 = bstart[b], s1 = bstart[b + 1];
    int cnt = s1 - s0;
    if (t < KEYS) histk[t] = 0;
    __syncthreads();
    bool fit = (cnt <= CAP);
    int cnt4 = cnt & ~3;
    auto key = [&](int e) {
        return (((e >> 17) & (NPW - 1)) << 1) | (((e & 0x1FFFF) >= nhalf) ? 1 : 0);
    };
    if (fit) {
        for (int i = t * 4; i < cnt4; i += 2048) {
            vint4u e4 = *(const vint4u*)(bucketed + s0 + i);
            lds_e[i + 0] = e4.x; atomicAdd(&histk[key(e4.x)], 1);
            lds_e[i + 1] = e4.y; atomicAdd(&histk[key(e4.y)], 1);
            lds_e[i + 2] = e4.z; atomicAdd(&histk[key(e4.z)], 1);
            lds_e[i + 3] = e4.w; atomicAdd(&histk[key(e4.w)], 1);
        }
        for (int i = cnt4 + t; i < cnt; i += 512) {
            int e = bucketed[s0 + i];
            lds_e[i] = e;
            atomicAdd(&histk[key(e)], 1);
        }
    } else {
        for (int i = t * 4; i < cnt4; i += 2048) {
            vint4u e4 = *(const vint4u*)(bucketed + s0 + i);
            atomicAdd(&histk[key(e4.x)], 1);
            atomicAdd(&histk[key(e4.y)], 1);
            atomicAdd(&histk[key(e4.z)], 1);
            atomicAdd(&histk[key(e4.w)], 1);
        }
        for (int i = cnt4 + t; i < cnt; i += 512)
            atomicAdd(&histk[key(bucketed[s0 + i])], 1);
    }
    __syncthreads();
    if (t == 0) {
        int run = 0;
        for (int k = 0; k < KEYS; ++k) { cur[k] = run; run += histk[k]; }
    }
    __syncthreads();
    if (t < NPW) {
        int node = b * NPW + t;
        if (node < n) {
            offs[node] = s0 + cur[2 * t];
            mid[node]  = s0 + cur[2 * t] + histk[2 * t];
            dinv[node] = 1.0f / sqrtf((float)(histk[2 * t] + histk[2 * t + 1] + 1));
        }
    }
    if (b == nb - 1 && t == 0) offs[n] = s1;
    __syncthreads();
    if (fit) {
        for (int i = t; i < cnt; i += 512) {
            int e = lds_e[i];
            int pos = atomicAdd(&cur[key(e)], 1);
            csr[s0 + pos] = e & 0x1FFFF;
        }
    } else {
        for (int i = t; i < cnt; i += 512) {
            int e = bucketed[s0 + i];
            int pos = atomicAdd(&cur[key(e)], 1);
            csr[s0 + pos] = e & 0x1FFFF;
        }
    }
}

// ---------------------------------------------------------------------------
// thread-per-node GEMMs: W index is lane-uniform -> scalar cache (no LDS);
// x/h streamed per-lane as float4; dinv pre-multiplied into output.
// ---------------------------------------------------------------------------
template <int BF16>
__global__ __launch_bounds__(256) void gemm1n(const float* __restrict__ x,
                                              const float* __restrict__ W1,
                                              const float* __restrict__ dinv,
                                              float* __restrict__ m1f,
                                              unsigned int* __restrict__ m1b, int n) {
    long long node = (long long)blockIdx.x * 256 + threadIdx.x;
    if (node >= n) return;
    float acc[HID];
#pragma unroll
    for (int c = 0; c < HID; ++c) acc[c] = 0.f;
    const float4* xr = (const float4*)(x + node * IN_CH);
    for (int k4 = 0; k4 < IN_CH / 4; ++k4) {
        float4 xv = xr[k4];
        const float* w0 = W1 + (k4 * 4) * HID;
#pragma unroll
        for (int c = 0; c < HID; ++c) acc[c] = fmaf(xv.x, w0[c], acc[c]);
#pragma unroll
        for (int c = 0; c < HID; ++c) acc[c] = fmaf(xv.y, w0[HID + c], acc[c]);
#pragma unroll
        for (int c = 0; c < HID; ++c) acc[c] = fmaf(xv.z, w0[2 * HID + c], acc[c]);
#pragma unroll
        for (int c = 0; c < HID; ++c) acc[c] = fmaf(xv.w, w0[3 * HID + c], acc[c]);
    }
    float di = dinv[node];
    if (BF16) {
        unsigned int* dst = m1b + (node << 4);
#pragma unroll
        for (int c = 0; c < HID / 2; ++c)
            dst[c] = pack_bf16(acc[2 * c] * di, acc[2 * c + 1] * di);
    } else {
        float4* dst = (float4*)(m1f + (node << 5));
#pragma unroll
        for (int c = 0; c < HID / 4; ++c) {
            float4 v;
            v.x = acc[4 * c] * di;     v.y = acc[4 * c + 1] * di;
            v.z = acc[4 * c + 2] * di; v.w = acc[4 * c + 3] * di;
            dst[c] = v;
        }
    }
}

template <int BF16>
__global__ __launch_bounds__(256) void gemm2n(const float* __restrict__ h,
                                              const float* __restrict__ W2,
                                              const float* __restrict__ dinv,
                                              float* __restrict__ m2f,
                                              unsigned int* __restrict__ m2b, int n) {
    long long node = (long long)blockIdx.x * 256 + threadIdx.x;
    if (node >= n) return;
    float acc[OUT_CH];
#pragma unroll
    for (int c = 0; c < OUT_CH; ++c) acc[c] = 0.f;
    const float4* hr = (const float4*)(h + (node << 5));
    for (int k4 = 0; k4 < HID / 4; ++k4) {
        float4 hv = hr[k4];
        const float* w0 = W2 + (k4 * 4) * OUT_CH;
#pragma unroll
        for (int c = 0; c < OUT_CH; ++c) acc[c] = fmaf(hv.x, w0[c], acc[c]);
#pragma unroll
        for (int c = 0; c < OUT_CH; ++c) acc[c] = fmaf(hv.y, w0[OUT_CH + c], acc[c]);
#pragma unroll
        for (int c = 0; c < OUT_CH; ++c) acc[c] = fmaf(hv.z, w0[2 * OUT_CH + c], acc[c]);
#pragma unroll
        for (int c = 0; c < OUT_CH; ++c) acc[c] = fmaf(hv.w, w0[3 * OUT_CH + c], acc[c]);
    }
    float di = dinv[node];
    if (BF16) {
        unsigned int* dst = m2b + (node << 3);
#pragma unroll
        for (int c = 0; c < OUT_CH / 2; ++c)
            dst[c] = pack_bf16(acc[2 * c] * di, acc[2 * c + 1] * di);
    } else {
        float4* dst = (float4*)(m2f + (node << 4));
#pragma unroll
        for (int c = 0; c < OUT_CH / 4; ++c) {
            float4 v;
            v.x = acc[4 * c] * di;     v.y = acc[4 * c + 1] * di;
            v.z = acc[4 * c + 2] * di; v.w = acc[4 * c + 3] * di;
            dst[c] = v;
        }
    }
}

// ---------------------------------------------------------------------------
// bf16 CSR gather aggregation, source-half split (L2-resident halves)
// ---------------------------------------------------------------------------
template <int MODE>
__global__ __launch_bounds__(256) void agg1_bf(const unsigned int* __restrict__ m1b,
                                               const int* __restrict__ csr,
                                               const int* __restrict__ offs,
                                               const int* __restrict__ mid,
                                               const float* __restrict__ dinv,
                                               const float* __restrict__ b1,
                                               float* __restrict__ h, int n) {
    int g = threadIdx.x >> 4;
    int c = threadIdx.x & 15;
    long long node = (long long)blockIdx.x * 16 + g;
    if (node >= n) return;
    int s, e1;
    if (MODE == 0)      { s = offs[node]; e1 = mid[node]; }
    else if (MODE == 1) { s = mid[node];  e1 = offs[node + 1]; }
    else                { s = offs[node]; e1 = offs[node + 1]; }
    float accL, accH;
    if (MODE == 0) { accL = 0.f; accH = 0.f; }
    else {
        unsigned int us = m1b[(node << 4) + c];      // self loop
        accL = bf_lo(us); accH = bf_hi(us);
    }
    for (; s + 7 < e1; s += 8) {
        vint4u a = *(const vint4u*)(csr + s);
        vint4u b = *(const vint4u*)(csr + s + 4);
        unsigned int u0 = m1b[((long long)a.x << 4) + c];
        unsigned int u1 = m1b[((long long)a.y << 4) + c];
        unsigned int u2 = m1b[((long long)a.z << 4) + c];
        unsigned int u3 = m1b[((long long)a.w << 4) + c];
        unsigned int u4 = m1b[((long long)b.x << 4) + c];
        unsigned int u5 = m1b[((long long)b.y << 4) + c];
        unsigned int u6 = m1b[((long long)b.z << 4) + c];
        unsigned int u7 = m1b[((long long)b.w << 4) + c];
        accL += bf_lo(u0); accH += bf_hi(u0);
        accL += bf_lo(u1); accH += bf_hi(u1);
        accL += bf_lo(u2); accH += bf_hi(u2);
        accL += bf_lo(u3); accH += bf_hi(u3);
        accL += bf_lo(u4); accH += bf_hi(u4);
        accL += bf_lo(u5); accH += bf_hi(u5);
        accL += bf_lo(u6); accH += bf_hi(u6);
        accL += bf_lo(u7); accH += bf_hi(u7);
    }
    for (; s < e1; ++s) {
        unsigned int u = m1b[((long long)csr[s] << 4) + c];
        accL += bf_lo(u); accH += bf_hi(u);
    }
    if (MODE == 0) {
        vfloat2 val; val.x = accL; val.y = accH;
        __builtin_nontemporal_store(val, (vfloat2*)(h + (node << 5) + 2 * c));
    } else {
        if (MODE == 1) {
            vfloat2 prev = __builtin_nontemporal_load((const vfloat2*)(h + (node << 5) + 2 * c));
            accL += prev.x; accH += prev.y;
        }
        float di = dinv[node];
        float vL = accL * di + b1[2 * c];
        float vH = accH * di + b1[2 * c + 1];
        vfloat2 val;
        val.x = vL > 0.f ? vL : 0.f;
        val.y = vH > 0.f ? vH : 0.f;
        *(vfloat2*)(h + (node << 5) + 2 * c) = val;
    }
}

__global__ __launch_bounds__(256) void agg2_bf(const unsigned int* __restrict__ m2b,
                                               const int* __restrict__ csr,
                                               const int* __restrict__ offs,
                                               const float* __restrict__ dinv,
                                               const float* __restrict__ b2,
                                               float* __restrict__ out, int n) {
    int g = threadIdx.x >> 3;
    int c = threadIdx.x & 7;
    long long node = (long long)blockIdx.x * 32 + g;
    if (node >= n) return;
    unsigned int us = m2b[(node << 3) + c];
    float accL = bf_lo(us), accH = bf_hi(us);
    int s = offs[node], e1 = offs[node + 1];
    for (; s + 7 < e1; s += 8) {
        vint4u a = *(const vint4u*)(csr + s);
        vint4u b = *(const vint4u*)(csr + s + 4);
        unsigned int u0 = m2b[((long long)a.x << 3) + c];
        unsigned int u1 = m2b[((long long)a.y << 3) + c];
        unsigned int u2 = m2b[((long long)a.z << 3) + c];
        unsigned int u3 = m2b[((long long)a.w << 3) + c];
        unsigned int u4 = m2b[((long long)b.x << 3) + c];
        unsigned int u5 = m2b[((long long)b.y << 3) + c];
        unsigned int u6 = m2b[((long long)b.z << 3) + c];
        unsigned int u7 = m2b[((long long)b.w << 3) + c];
        accL += bf_lo(u0); accH += bf_hi(u0);
        accL += bf_lo(u1); accH += bf_hi(u1);
        accL += bf_lo(u2); accH += bf_hi(u2);
        accL += bf_lo(u3); accH += bf_hi(u3);
        accL += bf_lo(u4); accH += bf_hi(u4);
        accL += bf_lo(u5); accH += bf_hi(u5);
        accL += bf_lo(u6); accH += bf_hi(u6);
        accL += bf_lo(u7); accH += bf_hi(u7);
    }
    for (; s < e1; ++s) {
        unsigned int u = m2b[((long long)csr[s] << 3) + c];
        accL += bf_lo(u); accH += bf_hi(u);
    }
    float di = dinv[node];
    vfloat2 val;
    val.x = accL * di + b2[2 * c];
    val.y = accH * di + b2[2 * c + 1];
    *(vfloat2*)(out + (node << 4) + 2 * c) = val;
}

// ---------------------------------------------------------------------------
// tier 2: windowed CSR fill path
// ---------------------------------------------------------------------------
__global__ __launch_bounds__(256) void count_edges(const void* ei, int* cnt,
                                                   long long E, const int* flag) {
    long long e0 = ((long long)blockIdx.x * 256 + threadIdx.x) * EPT;
    if (e0 >= E) return;
    int is64 = *flag;
    if (e0 + EPT <= E && (E & 7) == 0) {
        int c[EPT];
        load_idx8_nt(ei, E + e0, is64, c);
#pragma unroll
        for (int j = 0; j < EPT; ++j) atomicAdd(&cnt[c[j]], 1);
    } else {
        for (long long e = e0; e < E && e < e0 + EPT; ++e)
            atomicAdd(&cnt[load_idx(ei, E + e, is64)], 1);
    }
}

__global__ __launch_bounds__(256) void compute_dinv(const int* cnt, float* dinv, int n) {
    int i = blockIdx.x * 256 + threadIdx.x;
    if (i < n) dinv[i] = 1.0f / sqrtf((float)(cnt[i] + 1));
}

__global__ __launch_bounds__(256) void scan_partial(const int* cnt, int* partial, int n) {
    __shared__ int sd[256];
    int base = blockIdx.x * SCAN_CHUNK;
    int s = 0;
    for (int j = threadIdx.x; j < SCAN_CHUNK; j += 256) {
        int i = base + j;
        if (i < n) s += cnt[i];
    }
    sd[threadIdx.x] = s;
    __syncthreads();
    for (int off = 128; off > 0; off >>= 1) {
        if (threadIdx.x < off) sd[threadIdx.x] += sd[threadIdx.x + off];
        __syncthreads();
    }
    if (threadIdx.x == 0) partial[blockIdx.x] = sd[0];
}

__global__ void scan_serial(int* partial, int* offs, int nblk, int n) {
    if (threadIdx.x == 0 && blockIdx.x == 0) {
        int run = 0;
        for (int b = 0; b < nblk; ++b) { int t = partial[b]; partial[b] = run; run += t; }
        offs[n] = run;
    }
}

__global__ __launch_bounds__(256) void scan_final(const int* cnt, const int* partial,
                                                  int* offs, int n) {
    __shared__ int sd[256];
    int base = blockIdx.x * SCAN_CHUNK;
    int t = threadIdx.x;
    int loc[4]; int ts = 0;
#pragma unroll
    for (int j = 0; j < 4; ++j) {
        int i = base + t * 4 + j;
        loc[j] = (i < n) ? cnt[i] : 0;
        ts += loc[j];
    }
    sd[t] = ts;
    __syncthreads();
    for (int off = 1; off < 256; off <<= 1) {
        int v = (t >= off) ? sd[t - off] : 0;
        __syncthreads();
        sd[t] += v;
        __syncthreads();
    }
    int excl = sd[t] - ts + partial[blockIdx.x];
#pragma unroll
    for (int j = 0; j < 4; ++j) {
        int i = base + t * 4 + j;
        if (i < n) offs[i] = excl;
        excl += loc[j];
    }
}

__global__ __launch_bounds__(256) void copy_int(const int* src, int* dst, int n) {
    int i = blockIdx.x * 256 + threadIdx.x;
    if (i < n) dst[i] = src[i];
}

__global__ __launch_bounds__(256) void fill_csr_win(const void* ei, int* cursor, int* csr,
                                                    long long E, const int* flag,
                                                    int npw, int n) {
    int w = blockIdx.x & (NXCD - 1);
    int b = blockIdx.x >> 3;
    int lo = w * npw;
    int hi = lo + npw; if (hi > n) hi = n;
    long long e0 = ((long long)b * 256 + threadIdx.x) * EPT;
    if (e0 >= E) return;
    int is64 = *flag;
    if (e0 + EPT <= E && (E & 7) == 0) {
        int c[EPT];
        load_idx8_nt(ei, E + e0, is64, c);
#pragma unroll
        for (int j = 0; j < EPT; ++j) {
            if (c[j] >= lo && c[j] < hi) {
                int row = load_idx(ei, e0 + j, is64);
                int pos = atomicAdd(&cursor[c[j]], 1);
                csr[pos] = row;
            }
        }
    } else {
        for (long long e = e0; e < E && e < e0 + EPT; ++e) {
            int col = load_idx(ei, E + e, is64);
            if (col >= lo && col < hi) {
                int row = load_idx(ei, e, is64);
                int pos = atomicAdd(&cursor[col], 1);
                csr[pos] = row;
            }
        }
    }
}

// ---------------------------------------------------------------------------
// tier 3: scatter fallback (fp32, m pre-scaled)
// ---------------------------------------------------------------------------
__global__ __launch_bounds__(256) void scatter1(const float* __restrict__ m1s,
                                                const void* ei,
                                                float* __restrict__ h,
                                                long long E, const int* flag) {
    long long e = (long long)blockIdx.x * 8 + (threadIdx.x >> 5);
    int c = threadIdx.x & 31;
    if (e >= E) return;
    int is64 = *flag;
    int row = load_idx(ei, e, is64);
    int col = load_idx(ei, E + e, is64);
    atomicAdd(&h[(long long)col * HID + c], m1s[(long long)row * HID + c]);
}

__global__ __launch_bounds__(256) void fixup1(const float* __restrict__ m1s,
                                              const float* __restrict__ dinv,
                                              const float* __restrict__ b1,
                                              float* __restrict__ h, int n) {
    long long t = (long long)blockIdx.x * 256 + threadIdx.x;
    long long node = t >> 5; int c = (int)(t & 31);
    if (node >= n) return;
    float v = (h[node * HID + c] + m1s[node * HID + c]) * dinv[node] + b1[c];
    h[node * HID + c] = v > 0.f ? v : 0.f;
}

__global__ __launch_bounds__(256) void scatter2(const float* __restrict__ m2s,
                                                const void* ei,
                                                float* __restrict__ out,
                                                long long E, const int* flag) {
    long long e = (long long)blockIdx.x * 16 + (threadIdx.x >> 4);
    int c = threadIdx.x & 15;
    if (e >= E) return;
    int is64 = *flag;
    int row = load_idx(ei, e, is64);
    int col = load_idx(ei, E + e, is64);
    atomicAdd(&out[(long long)col * OUT_CH + c], m2s[(long long)row * OUT_CH + c]);
}

__global__ __launch_bounds__(256) void fixup2(const float* __restrict__ m2s,
                                              const float* __restrict__ dinv,
                                              const float* __restrict__ b2,
                                              float* __restrict__ out, int n) {
    long long t = (long long)blockIdx.x * 256 + threadIdx.x;
    long long node = t >> 4; int c = (int)(t & 15);
    if (node >= n) return;
    out[node * OUT_CH + c] = (out[node * OUT_CH + c] + m2s[node * OUT_CH + c]) * dinv[node] + b2[c];
}

// ---------------------------------------------------------------------------
extern "C" void kernel_launch(void* const* d_in, const int* in_sizes, int n_in,
                              void* d_out, int out_size, void* d_ws, size_t ws_size,
                              hipStream_t stream) {
    const float* x  = (const float*)d_in[0];
    const void*  ei = d_in[1];
    const float* W1 = (const float*)d_in[2];
    const float* b1 = (const float*)d_in[3];
    const float* W2 = (const float*)d_in[4];
    const float* b2 = (const float*)d_in[5];
    float* out = (float*)d_out;

    const int n = in_sizes[0] / IN_CH;           // 100000
    const long long E = in_sizes[1] / 2;         // 6400000
    const int nb = (n + NPW - 1) / NPW;          // 782
    const int nhalf = (n + 1) / 2;

    const long long chunkF = (((E + 511) / 512) + 7) & ~7LL;
    const int fbgrid = (int)((E + chunkF - 1) / chunkF);

    char* w = (char*)d_ws;
    size_t used = 0;
    auto carve = [&](size_t bytes) -> void* {
        void* p = (void*)(w + used);
        used += (bytes + 255) & ~(size_t)255;
        return p;
    };
    auto A = [](size_t b) -> size_t { return (b + 255) & ~(size_t)255; };

    int*   bstart  = (int*)carve((size_t)(NB_MAX + 1) * 4);
    int*   btot    = (int*)carve((size_t)NB_MAX * 4);
    float* dinv    = (float*)carve((size_t)n * 4);
    int*   flag    = (int*)carve(256);
    int*   offs    = (int*)carve((size_t)(n + 1) * 4);
    int*   mid     = (int*)carve((size_t)n * 4);
    int*   cnt     = (int*)carve((size_t)n * 4);
    int*   partial = (int*)carve(4096);
    const size_t base = used;

    const size_t bhistB = A((size_t)nb * fbgrid * 4);
    const size_t mbB    = A((size_t)n * HID * 2);   // bf16 m1 (reused as m2)
    const size_t hB     = A((size_t)n * HID * 4);
    const size_t needT1 = base + 2 * bhistB + 2 * A((size_t)E * 4) + mbB + hB;
    const size_t needT2 = base + A((size_t)E * 4) + mbB + hB;
    const size_t needT3 = base + 2 * A((size_t)n * HID * 4);
    const bool tier1 = (ws_size >= needT1) && (n <= 131071) && (nb <= NB_MAX);
    const bool tier2 = !tier1 && (ws_size >= needT2) && (n <= 131071);

    const int nblkN  = (n + 255) / 256;
    const int nblkEv = (int)((E + 256LL * EPT - 1) / (256LL * EPT));
    const int nblkSc = (n + SCAN_CHUNK - 1) / SCAN_CHUNK;
    const int nblkH  = (int)(((long long)n * HID + 255) / 256);
    const int nblkO  = (int)(((long long)n * OUT_CH + 255) / 256);

    detect_dtype<<<1, 64, 0, stream>>>(ei, E, n, flag);

    if (tier1) {
        int*   bhist    = (int*)carve((size_t)nb * fbgrid * 4);
        int*   bexcl    = (int*)carve((size_t)nb * fbgrid * 4);
        int*   bucketed = (int*)carve((size_t)E * 4);
        int*   csr      = (int*)carve((size_t)E * 4);
        __hip_bfloat16* m1b = (__hip_bfloat16*)carve((size_t)n * HID * 2);
        float* h  = (float*)carve((size_t)n * HID * 4);
        __hip_bfloat16* m2b = m1b;                 // m1b dead after agg1

        bucket_hist<<<fbgrid, FBT, 0, stream>>>(ei, E, flag, bhist, nb, chunkF, fbgrid);
        scan_blocks<<<nb, 256, 0, stream>>>(bhist, bexcl, btot, nb, fbgrid);
        scan_buckets<<<1, 1024, 0, stream>>>(btot, bstart, nb);
        fill_sort<<<fbgrid, FBT, 0, stream>>>(ei, E, flag, bhist, bexcl, bstart,
                                              bucketed, nb, chunkF, fbgrid);
        csr_sort<<<nb, 512, 0, stream>>>(bucketed, bstart, csr, offs, mid, dinv,
                                         nb, n, nhalf);

        gemm1n<1><<<nblkN, 256, 0, stream>>>(x, W1, dinv, nullptr,
                                             (unsigned int*)m1b, n);
        agg1_bf<0><<<(n + 15) / 16, 256, 0, stream>>>((const unsigned int*)m1b, csr,
                                                      offs, mid, dinv, b1, h, n);
        agg1_bf<1><<<(n + 15) / 16, 256, 0, stream>>>((const unsigned int*)m1b, csr,
                                                      offs, mid, dinv, b1, h, n);
        gemm2n<1><<<nblkN, 256, 0, stream>>>(h, W2, dinv, nullptr,
                                             (unsigned int*)m2b, n);
        agg2_bf<<<(n + 31) / 32, 256, 0, stream>>>((const unsigned int*)m2b, csr, offs,
                                                   dinv, b2, out, n);
    } else if (tier2) {
        int*   csr = (int*)carve((size_t)E * 4);
        __hip_bfloat16* m1b = (__hip_bfloat16*)carve((size_t)n * HID * 2);
        float* h  = (float*)carve((size_t)n * HID * 4);
        __hip_bfloat16* m2b = m1b;

        zero_int<<<nblkN, 256, 0, stream>>>(cnt, n);
        count_edges<<<nblkEv, 256, 0, stream>>>(ei, cnt, E, flag);
        compute_dinv<<<nblkN, 256, 0, stream>>>(cnt, dinv, n);
        scan_partial<<<nblkSc, 256, 0, stream>>>(cnt, partial, n);
        scan_serial<<<1, 64, 0, stream>>>(partial, offs, nblkSc, n);
        scan_final<<<nblkSc, 256, 0, stream>>>(cnt, partial, offs, n);
        copy_int<<<nblkN, 256, 0, stream>>>(offs, cnt, n);

        const int npw2 = (n + NXCD - 1) / NXCD;
        fill_csr_win<<<nblkEv * NXCD, 256, 0, stream>>>(ei, cnt, csr, E, flag, npw2, n);

        gemm1n<1><<<nblkN, 256, 0, stream>>>(x, W1, dinv, nullptr,
                                             (unsigned int*)m1b, n);
        agg1_bf<2><<<(n + 15) / 16, 256, 0, stream>>>((const unsigned int*)m1b, csr,
                                                      offs, offs, dinv, b1, h, n);
        gemm2n<1><<<nblkN, 256, 0, stream>>>(h, W2, dinv, nullptr,
                                             (unsigned int*)m2b, n);
        agg2_bf<<<(n + 31) / 32, 256, 0, stream>>>((const unsigned int*)m2b, csr, offs,
                                                   dinv, b2, out, n);
    } else if (ws_size >= needT3) {
        float* m1 = (float*)carve((size_t)n * HID * 4);
        float* h  = (float*)carve((size_t)n * HID * 4);
        float* m2 = m1;

        zero_int<<<nblkN, 256, 0, stream>>>(cnt, n);
        count_edges<<<nblkEv, 256, 0, stream>>>(ei, cnt, E, flag);
        compute_dinv<<<nblkN, 256, 0, stream>>>(cnt, dinv, n);

        gemm1n<0><<<nblkN, 256, 0, stream>>>(x, W1, dinv, m1, nullptr, n);
        zero_float<<<nblkH, 256, 0, stream>>>(h, (long long)n * HID);
        scatter1<<<(int)((E + 7) / 8), 256, 0, stream>>>(m1, ei, h, E, flag);
        fixup1<<<nblkH, 256, 0, stream>>>(m1, dinv, b1, h, n);
        gemm2n<0><<<nblkN, 256, 0, stream>>>(h, W2, dinv, m2, nullptr, n);
        zero_float<<<nblkO, 256, 0, stream>>>(out, (long long)n * OUT_CH);
        scatter2<<<(int)((E + 15) / 16), 256, 0, stream>>>(m2, ei, out, E, flag);
        fixup2<<<nblkO, 256, 0, stream>>>(m2, dinv, b2, out, n);
    }
}